// Round 1
// baseline (234.073 us; speedup 1.0000x reference)
//
#include <hip/hip_runtime.h>

// Sizes fixed by the problem.
#define B  32
#define S  128
#define IN 64
#define OUT 64
#define ROWS (B*S)      // 4096
#define K1  (S*IN)      // 8192

// ---------------------------------------------------------------------------
// Kernel 1: "prep"
//   blocks 0..15   : U1T[o][o2] = sum_t W1[o2, t*64+o]           (4096 threads)
//   blocks 16..271 : per-row Ab = h.W0a^T + b0, C = h.W0b^T,
//                    Df = (h.Ws^T + bs) - Ab - C                  (16 rows/block)
// ---------------------------------------------------------------------------
__global__ __launch_bounds__(256) void prep_kernel(
    const float* __restrict__ h,  const float* __restrict__ W0,
    const float* __restrict__ b0, const float* __restrict__ Ws,
    const float* __restrict__ bs, const float* __restrict__ W1,
    float* __restrict__ U1T, float* __restrict__ Ab,
    float* __restrict__ Df,  float* __restrict__ C)
{
    const int bid = blockIdx.x, tid = threadIdx.x;

    if (bid < 16) {
        // U1T: thread g -> (o2, o). Lanes have consecutive o -> coalesced reads.
        const int g  = bid * 256 + tid;        // 0..4095
        const int o2 = g >> 6, o = g & 63;
        const float* w = W1 + o2 * K1 + o;
        float acc = 0.f;
        #pragma unroll
        for (int t = 0; t < S; ++t) acc += w[t * IN];
        U1T[o * 64 + o2] = acc;                // transposed store (scattered, tiny)
        return;
    }

    // Row section: stage transposed weights with +1 pad -> conflict-free reads.
    __shared__ float sW0aT[64][65];
    __shared__ float sW0bT[64][65];
    __shared__ float sWsT [64][65];
    __shared__ float sH   [16][64];

    const int rb = bid - 16;                   // 0..255, 16 rows each
    for (int idx = tid; idx < 64 * 128; idx += 256) {
        const int o = idx >> 7, col = idx & 127;
        const float v = W0[idx];
        if (col < 64) sW0aT[col][o] = v;
        else          sW0bT[col - 64][o] = v;
    }
    for (int idx = tid; idx < 64 * 64; idx += 256) {
        sWsT[idx & 63][idx >> 6] = Ws[idx];
    }
    for (int idx = tid; idx < 16 * 64; idx += 256) {
        sH[idx >> 6][idx & 63] = h[rb * 1024 + idx];
    }
    __syncthreads();

    const int wave = tid >> 6, lane = tid & 63;
    const float b0v = b0[lane], bsv = bs[lane];
    for (int r = wave; r < 16; r += 4) {
        float a = 0.f, c = 0.f, sf = 0.f;
        #pragma unroll
        for (int i = 0; i < 64; ++i) {
            const float hi = sH[r][i];         // LDS broadcast (free)
            a  += hi * sW0aT[i][lane];         // consecutive lanes (free)
            c  += hi * sW0bT[i][lane];
            sf += hi * sWsT [i][lane];
        }
        const int row = rb * 16 + r;
        const float ab = a + b0v;
        Ab[row * 64 + lane] = ab;
        C [row * 64 + lane] = c;
        Df[row * 64 + lane] = sf + bsv - ab - c;
    }
}

// ---------------------------------------------------------------------------
// Kernel 2: "dcalc" — D[b,o2] = sum_k C[b,k] * W1[o2,k], one block per b.
// ---------------------------------------------------------------------------
__global__ __launch_bounds__(256) void dcalc_kernel(
    const float* __restrict__ C, const float* __restrict__ W1,
    float* __restrict__ D)
{
    __shared__ float sC[K1];
    const int b = blockIdx.x, tid = threadIdx.x;
    for (int idx = tid; idx < K1; idx += 256) sC[idx] = C[b * K1 + idx];
    __syncthreads();

    const int wave = tid >> 6, lane = tid & 63;
    for (int o2 = wave; o2 < 64; o2 += 4) {
        const float* w = W1 + o2 * K1;
        float acc = 0.f;
        for (int k = lane; k < K1; k += 64)    // coalesced W1, 2-lane/bank LDS (free)
            acc += sC[k] * w[k];
        #pragma unroll
        for (int off = 32; off; off >>= 1) acc += __shfl_xor(acc, off);
        if (lane == 0) D[b * 64 + o2] = acc;
    }
}

// ---------------------------------------------------------------------------
// Kernel 3: "finalk" — one block per s.
//   out[b,s,o2] = D[b,o2] + b1[o2]
//               + sum_o Ab[b,s,o]*U1T[o][o2] + Df[b,s,o]*W1[o2, s*64+o]
// ---------------------------------------------------------------------------
__global__ __launch_bounds__(256) void final_kernel(
    const float* __restrict__ W1, const float* __restrict__ b1,
    const float* __restrict__ U1Tg, const float* __restrict__ Ab,
    const float* __restrict__ Df,   const float* __restrict__ D,
    float* __restrict__ out)
{
    __shared__ float sW1T[64][65];
    __shared__ float sU1T[64][65];
    __shared__ float sAb [32][64];
    __shared__ float sDf [32][64];

    const int s = blockIdx.x, tid = threadIdx.x;

    for (int idx = tid; idx < 64 * 64; idx += 256) {
        const int o2 = idx >> 6, o = idx & 63;             // coalesced over o
        sW1T[o][o2] = W1[o2 * K1 + s * 64 + o];            // pad-65 write: no conflict
    }
    for (int idx = tid; idx < 64 * 64; idx += 256) {
        const int o = idx >> 6, o2 = idx & 63;             // coalesced over o2
        sU1T[o][o2] = U1Tg[idx];
    }
    for (int idx = tid; idx < 32 * 64; idx += 256) {
        const int b = idx >> 6, o = idx & 63;
        sAb[b][o] = Ab[(b * S + s) * 64 + o];
        sDf[b][o] = Df[(b * S + s) * 64 + o];
    }
    __syncthreads();

    const int wave = tid >> 6, lane = tid & 63;            // lane = o2
    const float b1v = b1[lane];
    for (int b = wave; b < B; b += 4) {
        float acc = D[b * 64 + lane] + b1v;
        #pragma unroll
        for (int o = 0; o < 64; ++o) {
            acc += sAb[b][o] * sU1T[o][lane]               // broadcast * consecutive
                 + sDf[b][o] * sW1T[o][lane];
        }
        out[(b * S + s) * 64 + lane] = acc;                // coalesced store
    }
}

// ---------------------------------------------------------------------------
extern "C" void kernel_launch(void* const* d_in, const int* in_sizes, int n_in,
                              void* d_out, int out_size, void* d_ws, size_t ws_size,
                              hipStream_t stream)
{
    const float* h  = (const float*)d_in[0];
    const float* W0 = (const float*)d_in[1];
    const float* b0 = (const float*)d_in[2];
    const float* Ws = (const float*)d_in[3];
    const float* bs = (const float*)d_in[4];
    const float* W1 = (const float*)d_in[5];
    const float* b1 = (const float*)d_in[6];
    float* out = (float*)d_out;

    float* ws  = (float*)d_ws;
    float* U1T = ws;                       // 4096
    float* Ab  = U1T + 64 * 64;            // 262144
    float* Df  = Ab  + ROWS * 64;          // 262144
    float* C   = Df  + ROWS * 64;          // 262144
    float* D   = C   + ROWS * 64;          // 2048
    // total: 792576 floats ~= 3.02 MB of d_ws

    prep_kernel <<<272, 256, 0, stream>>>(h, W0, b0, Ws, bs, W1, U1T, Ab, Df, C);
    dcalc_kernel<<<B,   256, 0, stream>>>(C, W1, D);
    final_kernel<<<S,   256, 0, stream>>>(W1, b1, U1T, Ab, Df, D, out);
}

// Round 2
// 60.034 us; speedup vs baseline: 3.8990x; 3.8990x over previous
//
#include <hip/hip_runtime.h>

// Sizes fixed by the problem.
#define B  32
#define S  128
#define IN 64
#define OUT 64
#define ROWS (B*S)      // 4096
#define K1  (S*IN)      // 8192
#define KCHUNKS 64      // dcalc K-split: 64 blocks x 128 k each

// ---------------------------------------------------------------------------
// Kernel 1: "prep"
//   blocks 0..15   : U1T[o][o2] = sum_t W1[o2, t*64+o]           (4096 threads)
//   blocks 16..271 : per-row Ab = h.W0a^T + b0, C = h.W0b^T,
//                    Df = (h.Ws^T + bs) - Ab - C                  (16 rows/block)
// ---------------------------------------------------------------------------
__global__ __launch_bounds__(256) void prep_kernel(
    const float* __restrict__ h,  const float* __restrict__ W0,
    const float* __restrict__ b0, const float* __restrict__ Ws,
    const float* __restrict__ bs, const float* __restrict__ W1,
    float* __restrict__ U1T, float* __restrict__ Ab,
    float* __restrict__ Df,  float* __restrict__ C)
{
    const int bid = blockIdx.x, tid = threadIdx.x;

    if (bid < 16) {
        // U1T: thread g -> (o2, o). Lanes have consecutive o -> coalesced reads.
        const int g  = bid * 256 + tid;        // 0..4095
        const int o2 = g >> 6, o = g & 63;
        const float* w = W1 + o2 * K1 + o;
        float acc = 0.f;
        #pragma unroll
        for (int t = 0; t < S; ++t) acc += w[t * IN];
        U1T[o * 64 + o2] = acc;                // transposed store (scattered, tiny)
        return;
    }

    // Row section: stage transposed weights with +1 pad -> conflict-free reads.
    __shared__ float sW0aT[64][65];
    __shared__ float sW0bT[64][65];
    __shared__ float sWsT [64][65];
    __shared__ float sH   [16][64];

    const int rb = bid - 16;                   // 0..255, 16 rows each
    for (int idx = tid; idx < 64 * 128; idx += 256) {
        const int o = idx >> 7, col = idx & 127;
        const float v = W0[idx];
        if (col < 64) sW0aT[col][o] = v;
        else          sW0bT[col - 64][o] = v;
    }
    for (int idx = tid; idx < 64 * 64; idx += 256) {
        sWsT[idx & 63][idx >> 6] = Ws[idx];
    }
    for (int idx = tid; idx < 16 * 64; idx += 256) {
        sH[idx >> 6][idx & 63] = h[rb * 1024 + idx];
    }
    __syncthreads();

    const int wave = tid >> 6, lane = tid & 63;
    const float b0v = b0[lane], bsv = bs[lane];
    for (int r = wave; r < 16; r += 4) {
        float a = 0.f, c = 0.f, sf = 0.f;
        #pragma unroll
        for (int i = 0; i < 64; ++i) {
            const float hi = sH[r][i];         // LDS broadcast (free)
            a  += hi * sW0aT[i][lane];         // consecutive lanes (free)
            c  += hi * sW0bT[i][lane];
            sf += hi * sWsT [i][lane];
        }
        const int row = rb * 16 + r;
        const float ab = a + b0v;
        Ab[row * 64 + lane] = ab;
        C [row * 64 + lane] = c;
        Df[row * 64 + lane] = sf + bsv - ab - c;
    }
}

// ---------------------------------------------------------------------------
// Kernel 2: "dcalc" — K-split partial GEMM.
//   block kc owns k in [kc*128, kc*128+128):
//     P[kc, b*64+o2] = sum_{k in chunk} C[b,k] * W1[o2,k]
//   64 blocks, 256 threads; thread = (wave,lane) -> o2=lane, b = wave+4p.
// ---------------------------------------------------------------------------
__global__ __launch_bounds__(256) void dcalc_kernel(
    const float* __restrict__ C, const float* __restrict__ W1,
    float* __restrict__ P)
{
    __shared__ float sC  [B][128];     // 16 KB
    __shared__ float sW1T[128][65];    // 33.3 KB, padded: lane=o2 reads conflict-free

    const int kc = blockIdx.x, tid = threadIdx.x;
    const int k0 = kc * 128;

    for (int idx = tid; idx < B * 128; idx += 256) {
        const int b = idx >> 7, k = idx & 127;             // coalesced over k
        sC[b][k] = C[b * K1 + k0 + k];
    }
    for (int idx = tid; idx < 64 * 128; idx += 256) {
        const int o2 = idx >> 7, k = idx & 127;            // coalesced over k
        sW1T[k][o2] = W1[o2 * K1 + k0 + k];                // stride-65 write: banks walk
    }
    __syncthreads();

    const int wave = tid >> 6, lane = tid & 63;            // lane = o2
    float acc[8] = {0.f};                                  // b = wave + 4p : ILP-8
    for (int k = 0; k < 128; ++k) {
        const float w = sW1T[k][lane];                     // 2 lanes/bank: free
        #pragma unroll
        for (int p = 0; p < 8; ++p)
            acc[p] += sC[wave + 4 * p][k] * w;             // broadcast: free
    }
    #pragma unroll
    for (int p = 0; p < 8; ++p)
        P[kc * (B * 64) + (wave + 4 * p) * 64 + lane] = acc[p];
}

// ---------------------------------------------------------------------------
// Kernel 3: "finalk" — one block per s.
//   out[b,s,o2] = (sum_p P[p,b,o2]) + b1[o2]
//               + sum_o Ab[b,s,o]*U1T[o][o2] + Df[b,s,o]*W1[o2, s*64+o]
// ---------------------------------------------------------------------------
__global__ __launch_bounds__(256) void final_kernel(
    const float* __restrict__ W1, const float* __restrict__ b1,
    const float* __restrict__ U1Tg, const float* __restrict__ Ab,
    const float* __restrict__ Df,   const float* __restrict__ P,
    float* __restrict__ out)
{
    __shared__ float sW1T[64][65];
    __shared__ float sU1T[64][65];
    __shared__ float sAb [32][64];
    __shared__ float sDf [32][64];

    const int s = blockIdx.x, tid = threadIdx.x;

    for (int idx = tid; idx < 64 * 64; idx += 256) {
        const int o2 = idx >> 6, o = idx & 63;             // coalesced over o
        sW1T[o][o2] = W1[o2 * K1 + s * 64 + o];            // pad-65 write: no conflict
    }
    for (int idx = tid; idx < 64 * 64; idx += 256) {
        const int o = idx >> 6, o2 = idx & 63;             // coalesced over o2
        sU1T[o][o2] = U1Tg[idx];
    }
    for (int idx = tid; idx < 32 * 64; idx += 256) {
        const int b = idx >> 6, o = idx & 63;
        sAb[b][o] = Ab[(b * S + s) * 64 + o];
        sDf[b][o] = Df[(b * S + s) * 64 + o];
    }
    __syncthreads();

    const int wave = tid >> 6, lane = tid & 63;            // lane = o2
    const float b1v = b1[lane];
    for (int b = wave; b < B; b += 4) {
        // fold the K-split reduction of D into the accumulator init
        float acc = b1v;
        #pragma unroll 8
        for (int p = 0; p < KCHUNKS; ++p)
            acc += P[p * (B * 64) + b * 64 + lane];        // coalesced, L2-resident
        #pragma unroll
        for (int o = 0; o < 64; ++o) {
            acc += sAb[b][o] * sU1T[o][lane]               // broadcast * consecutive
                 + sDf[b][o] * sW1T[o][lane];
        }
        out[(b * S + s) * 64 + lane] = acc;                // coalesced store
    }
}

// ---------------------------------------------------------------------------
extern "C" void kernel_launch(void* const* d_in, const int* in_sizes, int n_in,
                              void* d_out, int out_size, void* d_ws, size_t ws_size,
                              hipStream_t stream)
{
    const float* h  = (const float*)d_in[0];
    const float* W0 = (const float*)d_in[1];
    const float* b0 = (const float*)d_in[2];
    const float* Ws = (const float*)d_in[3];
    const float* bs = (const float*)d_in[4];
    const float* W1 = (const float*)d_in[5];
    const float* b1 = (const float*)d_in[6];
    float* out = (float*)d_out;

    float* ws  = (float*)d_ws;
    float* U1T = ws;                       // 4096
    float* Ab  = U1T + 64 * 64;            // 262144
    float* Df  = Ab  + ROWS * 64;          // 262144
    float* C   = Df  + ROWS * 64;          // 262144
    float* P   = C   + ROWS * 64;          // 64*2048 = 131072
    // total: 921600 floats ~= 3.69 MB of d_ws

    prep_kernel <<<272,     256, 0, stream>>>(h, W0, b0, Ws, bs, W1, U1T, Ab, Df, C);
    dcalc_kernel<<<KCHUNKS, 256, 0, stream>>>(C, W1, P);
    final_kernel<<<S,       256, 0, stream>>>(W1, b1, U1T, Ab, Df, P, out);
}

// Round 9
// 52.627 us; speedup vs baseline: 4.4478x; 1.1407x over previous
//
#include <hip/hip_runtime.h>

// Sizes fixed by the problem.
#define B   32
#define S   128
#define IN  64
#define ROWS (B*S)      // 4096
#define K1  (S*IN)      // 8192
#define KCH 64          // D-GEMM K-split: 64 blocks x 128 k each

__device__ __forceinline__ int rfl(int x) { return __builtin_amdgcn_readfirstlane(x); }

// ---------------------------------------------------------------------------
// Kernel 1: "prep" — 256 blocks, 16 rows each. LDS-free.
//   lane = o. Reference contracts 'bsi,oi->bso': o is the ROW of W0/Ws,
//   i the column. So lane's weights are row `lane` -> per-lane contiguous
//   float4 row loads (L2-resident, reused by all 256 blocks).
//   h rows are wave-uniform -> scalar (SMEM) loads.
//   Ab = h.W0a^T + b0;  C = h.W0b^T;  Df = (h.Ws^T + bs) - Ab - C
// ---------------------------------------------------------------------------
__global__ __launch_bounds__(256) void prep_kernel(
    const float* __restrict__ h,  const float* __restrict__ W0,
    const float* __restrict__ b0, const float* __restrict__ Ws,
    const float* __restrict__ bs,
    float* __restrict__ Ab, float* __restrict__ Df, float* __restrict__ C)
{
    const int tid  = threadIdx.x;
    const int lane = tid & 63;                 // = o
    const int w    = rfl(tid >> 6);            // wave id, uniform
    const int rb   = blockIdx.x;               // 0..255
    const int row0 = rb * 16 + w * 4;          // this wave's 4 rows (uniform)

    // row pointers: W0 row `lane` = [W0a_row (64) | W0b_row (64)]
    const float4* w0row = (const float4*)(W0 + (size_t)lane * 128);
    const float4* wsrow = (const float4*)(Ws + (size_t)lane * 64);

    float a[4] = {0,0,0,0}, c[4] = {0,0,0,0}, sf[4] = {0,0,0,0};

    #pragma unroll
    for (int ic = 0; ic < 4; ++ic) {           // i-chunks of 16
        const int i0 = ic * 16;
        float wa[16], wb[16], wsv[16];
        #pragma unroll
        for (int q = 0; q < 4; ++q) {          // per-lane contiguous 16B loads
            const float4 va = w0row[ic * 4 + q];        // W0a[lane][i0+4q..+3]
            const float4 vb = w0row[16 + ic * 4 + q];   // W0b[lane][i0+4q..+3]
            const float4 vs = wsrow[ic * 4 + q];        // Ws [lane][i0+4q..+3]
            wa [q*4] = va.x; wa [q*4+1] = va.y; wa [q*4+2] = va.z; wa [q*4+3] = va.w;
            wb [q*4] = vb.x; wb [q*4+1] = vb.y; wb [q*4+2] = vb.z; wb [q*4+3] = vb.w;
            wsv[q*4] = vs.x; wsv[q*4+1] = vs.y; wsv[q*4+2] = vs.z; wsv[q*4+3] = vs.w;
        }
        #pragma unroll
        for (int r = 0; r < 4; ++r) {
            const float* hp = h + (size_t)(row0 + r) * 64 + i0;  // uniform -> s_load
            #pragma unroll
            for (int j = 0; j < 16; ++j) {
                const float hv = hp[j];
                a [r] += hv * wa [j];
                c [r] += hv * wb [j];
                sf[r] += hv * wsv[j];
            }
        }
    }
    const float b0v = b0[lane], bsv = bs[lane];
    #pragma unroll
    for (int r = 0; r < 4; ++r) {
        const int row = row0 + r;
        const float ab = a[r] + b0v;
        Ab[row * 64 + lane] = ab;              // coalesced stores
        C [row * 64 + lane] = c[r];
        Df[row * 64 + lane] = sf[r] + bsv - ab - c[r];
    }
}

// ---------------------------------------------------------------------------
// Kernel 2: "mid" — 80 blocks, LDS-free.
//   blocks 0..63 : P[b][o2][kc] = sum_{k in chunk kc} C[b,k]*W1[o2,k]
//                  lane = o2 reads its W1 row as float4 (per-lane contiguous);
//                  C[b,k] wave-uniform -> s_load.
//   blocks 64..79: U1T[o][o2] = sum_t W1[o2, t*64+o]
// ---------------------------------------------------------------------------
__global__ __launch_bounds__(256) void mid_kernel(
    const float* __restrict__ C, const float* __restrict__ W1,
    float* __restrict__ P, float* __restrict__ U1T)
{
    const int bid = blockIdx.x, tid = threadIdx.x;

    if (bid >= KCH) {                          // U1T section
        const int g  = (bid - KCH) * 256 + tid;  // 0..4095
        const int o2 = g >> 6, o = g & 63;
        const float* wp = W1 + (size_t)o2 * K1 + o;
        float acc = 0.f;
        #pragma unroll
        for (int t = 0; t < S; ++t) acc += wp[t * IN];   // coalesced across lanes
        U1T[o * 64 + o2] = acc;
        return;
    }

    const int lane = tid & 63;                 // = o2
    const int w    = rfl(tid >> 6);            // uniform
    const int k0   = bid * 128;
    const float4* wrow = (const float4*)(W1 + (size_t)lane * K1 + k0);

    float acc[8] = {0,0,0,0,0,0,0,0};          // b = w + 4p
    for (int kq = 0; kq < 32; ++kq) {
        const float4 w4 = wrow[kq];            // per-lane contiguous, L2-resident
        #pragma unroll
        for (int p = 0; p < 8; ++p) {
            const float* cb = C + (size_t)(w + 4 * p) * K1 + k0 + kq * 4; // uniform -> s_load
            acc[p] += cb[0] * w4.x + cb[1] * w4.y + cb[2] * w4.z + cb[3] * w4.w;
        }
    }
    #pragma unroll
    for (int p = 0; p < 8; ++p)
        P[(((w + 4 * p) * 64) + lane) * 64 + bid] = acc[p];
}

// ---------------------------------------------------------------------------
// Kernel 3: "finalk" — 128 blocks (one per s), LDS-free.
//   out[b,s,o2] = sum_p P[b][o2][p] + b1[o2]
//               + sum_o Ab[b,s,o]*U1T[o][o2] + Df[b,s,o]*W1[o2, s*64+o]
//   U1T/W1 columns cached in VGPRs (two 32-wide halves); Ab/Df rows uniform.
// ---------------------------------------------------------------------------
__global__ __launch_bounds__(256) void final_kernel(
    const float* __restrict__ W1, const float* __restrict__ b1,
    const float* __restrict__ U1T, const float* __restrict__ Ab,
    const float* __restrict__ Df,  const float* __restrict__ P,
    float* __restrict__ out)
{
    const int s    = blockIdx.x;
    const int tid  = threadIdx.x;
    const int lane = tid & 63;                 // = o2
    const int w    = rfl(tid >> 6);            // uniform

    float acc[8];
    const float b1v = b1[lane];

    // D-fold: P[b][o2][0..63] is per-lane contiguous -> 16x b128 per b
    #pragma unroll
    for (int p = 0; p < 8; ++p) {
        const int b = w + 4 * p;
        const float4* pp = (const float4*)(P + ((size_t)(b * 64 + lane)) * 64);
        float s0 = 0, s1 = 0, s2 = 0, s3 = 0;
        #pragma unroll
        for (int q = 0; q < 16; ++q) {
            const float4 v = pp[q];
            s0 += v.x; s1 += v.y; s2 += v.z; s3 += v.w;
        }
        acc[p] = b1v + ((s0 + s1) + (s2 + s3));
    }

    // two 32-wide o-halves to keep VGPRs ~<110
    #pragma unroll
    for (int hh = 0; hh < 2; ++hh) {
        const int o0 = hh * 32;
        float u[32], wc[32];
        #pragma unroll
        for (int j = 0; j < 32; ++j)
            u[j] = U1T[(o0 + j) * 64 + lane];  // coalesced across lanes
        const float4* wrow = (const float4*)(W1 + (size_t)lane * K1 + s * 64 + o0);
        #pragma unroll
        for (int q = 0; q < 8; ++q) {          // per-lane contiguous 128B
            const float4 v = wrow[q];
            wc[q * 4] = v.x; wc[q * 4 + 1] = v.y; wc[q * 4 + 2] = v.z; wc[q * 4 + 3] = v.w;
        }
        #pragma unroll
        for (int p = 0; p < 8; ++p) {
            const int b = w + 4 * p;
            const float* ap = Ab + ((size_t)(b * S + s)) * 64 + o0;  // uniform -> s_load
            const float* dp = Df + ((size_t)(b * S + s)) * 64 + o0;
            float t0 = 0.f;
            #pragma unroll
            for (int j = 0; j < 32; ++j)
                t0 += ap[j] * u[j] + dp[j] * wc[j];
            acc[p] += t0;
        }
    }

    #pragma unroll
    for (int p = 0; p < 8; ++p)
        out[((size_t)((w + 4 * p) * S + s)) * 64 + lane] = acc[p];   // coalesced
}

// ---------------------------------------------------------------------------
extern "C" void kernel_launch(void* const* d_in, const int* in_sizes, int n_in,
                              void* d_out, int out_size, void* d_ws, size_t ws_size,
                              hipStream_t stream)
{
    const float* h  = (const float*)d_in[0];
    const float* W0 = (const float*)d_in[1];
    const float* b0 = (const float*)d_in[2];
    const float* Ws = (const float*)d_in[3];
    const float* bs = (const float*)d_in[4];
    const float* W1 = (const float*)d_in[5];
    const float* b1 = (const float*)d_in[6];
    float* out = (float*)d_out;

    float* ws  = (float*)d_ws;
    float* U1T = ws;                       // 4096
    float* Ab  = U1T + 64 * 64;            // 262144
    float* Df  = Ab  + ROWS * 64;          // 262144
    float* C   = Df  + ROWS * 64;          // 262144
    float* P   = C   + ROWS * 64;          // 2048*64 = 131072
    // total: ~3.5 MB of d_ws; every element we read is written first each call.

    prep_kernel <<<256, 256, 0, stream>>>(h, W0, b0, Ws, bs, Ab, Df, C);
    mid_kernel  <<<KCH + 16, 256, 0, stream>>>(C, W1, P, U1T);
    final_kernel<<<S,       256, 0, stream>>>(W1, b1, U1T, Ab, Df, P, out);
}